// Round 2
// baseline (2150.724 us; speedup 1.0000x reference)
//
#include <hip/hip_runtime.h>
#include <math.h>

constexpr int RVQ_N = 262144;
constexpr int RVQ_D = 64;
constexpr int RVQ_L = 4;
constexpr int RVQ_K = 1024;

typedef __attribute__((ext_vector_type(8))) short short8;
typedef __attribute__((ext_vector_type(4))) float floatx4;

// ---- bf16 split helpers (RNE) ----
__device__ __forceinline__ unsigned short f2bf(float f) {
  unsigned int u = __float_as_uint(f);
  u += 0x7fffu + ((u >> 16) & 1u);
  return (unsigned short)(u >> 16);
}
__device__ __forceinline__ float bf2f(unsigned short h) {
  return __uint_as_float(((unsigned int)h) << 16);
}
__device__ __forceinline__ void split2(float x, unsigned short& h0,
                                       unsigned short& h1) {
  h0 = f2bf(x);
  float r1 = x - bf2f(h0);
  h1 = f2bf(r1);
}
__device__ __forceinline__ void load8(const float* p, float* v) {
  float4 a = *(const float4*)p;
  float4 b = *(const float4*)(p + 4);
  v[0] = a.x; v[1] = a.y; v[2] = a.z; v[3] = a.w;
  v[4] = b.x; v[5] = b.y; v[6] = b.z; v[7] = b.w;
}

// top-2 insert helper: median of {p1,p2,u} is the new second-best (p1<=p2).
__device__ __forceinline__ unsigned med3u(unsigned a, unsigned b, unsigned c) {
  unsigned d;
  asm("v_med3_u32 %0, %1, %2, %3" : "=v"(d) : "v"(a), "v"(b), "v"(c));
  return d;
}

// ---------------------------------------------------------------------------
// Prep 1: split -2*codebook into hi/mid bf16 arrays [L*K*D each]
// ---------------------------------------------------------------------------
__global__ __launch_bounds__(256) void rvq_prep_split(
    const float* __restrict__ cb, unsigned short* __restrict__ bh,
    unsigned short* __restrict__ bm) {
  int i = blockIdx.x * 256 + threadIdx.x;
  float c2 = -2.0f * cb[i];
  unsigned short h0, h1;
  split2(c2, h0, h1);
  bh[i] = h0;
  bm[i] = h1;
}

// ---------------------------------------------------------------------------
// Prep 2: per-center squared norms. Raw (R1-verbatim, for rescue) + biased
// (+256 so MFMA scores = ||r-c||^2 + 256 > 0 -> uint-compare monotone).
// ---------------------------------------------------------------------------
__global__ __launch_bounds__(256) void rvq_cnorm_kernel(
    const float* __restrict__ cb, float* __restrict__ cnorm,
    float* __restrict__ cnormB) {
  int i = blockIdx.x * blockDim.x + threadIdx.x;
  const float* c = cb + (size_t)i * RVQ_D;
  float a0 = 0.f, a1 = 0.f, a2 = 0.f, a3 = 0.f;
#pragma unroll
  for (int d = 0; d < RVQ_D; d += 4) {
    float4 v = *reinterpret_cast<const float4*>(c + d);
    a0 = fmaf(v.x, v.x, a0);
    a1 = fmaf(v.y, v.y, a1);
    a2 = fmaf(v.z, v.z, a2);
    a3 = fmaf(v.w, v.w, a3);
  }
  float s = (a0 + a1) + (a2 + a3);
  cnorm[i] = s;
  cnormB[i] = s + 256.0f;
}

// B-tile fragment loader: hi/mid x 2 dim-octets + biased cnorm
__device__ __forceinline__ void load_bt(const unsigned short* __restrict__ bh,
                                        const unsigned short* __restrict__ bmp,
                                        const float* __restrict__ cnl, int nt,
                                        int m, int q, short8 (&b)[2][2],
                                        float& cc) {
  size_t rowoff = (size_t)(nt * 16 + m) * RVQ_D + q * 8;
  b[0][0] = *(const short8*)(bh + rowoff);
  b[0][1] = *(const short8*)(bh + rowoff + 32);
  b[1][0] = *(const short8*)(bmp + rowoff);
  b[1][1] = *(const short8*)(bmp + rowoff + 32);
  cc = cnl[nt * 16 + m];
}

// ---------------------------------------------------------------------------
// Main fused kernel. No LDS, no barriers. Each wave owns 64 points; each
// level's K-scan is done in TWO passes over the B stream, each pass covering
// half of the wave's A tiles (t in {0,1} then {2,3}) -- halves the live
// fragment state so the wave fits 4 waves/SIMD (<=128 regs).
// The fp32 rescue is STREAMED (no r_[64] array): the residual chunk
// ((f-c0)-c1)-c2 is recomputed 4 floats at a time inside each pass, with
// identical accumulator chains / op order to the original -> bit-identical
// scores, but peak live registers drop by ~60. This removes the R1 spill
// (FETCH/WRITE +370MB scratch traffic) while keeping the occupancy win.
// Packed-uint top-2 scan nominates; exact fp32 rescue decides.
// ---------------------------------------------------------------------------
__global__ __launch_bounds__(256, 4) void rvq_mfma_kernel(
    const float* __restrict__ feat, const float* __restrict__ cb,
    const unsigned short* __restrict__ cb_hi,
    const unsigned short* __restrict__ cb_mid,
    const float* __restrict__ cnorm, const float* __restrict__ cnormB,
    float* __restrict__ out_q, float* __restrict__ out_idx) {
  const int tid = threadIdx.x;
  const int lane = tid & 63;
  const int wave = tid >> 6;
  const int m = lane & 15;  // column (B center / C col / A row)
  const int q = lane >> 4;  // quad (k-octet / C row-group)
  const int base = blockIdx.x * 256 + wave * 64;  // wave's first point
  const int g = base + lane;                      // this lane's own point

  int ci0 = 0, ci1 = 0, ci2 = 0;  // chosen-index chain (own point)

  // products kept: hi*hi, hi*mid, mid*hi
  constexpr int AC[3] = {0, 0, 1};
  constexpr int BC[3] = {0, 1, 0};

#pragma unroll
  for (int l = 0; l < RVQ_L; ++l) {
    const unsigned short* bh = cb_hi + (size_t)l * RVQ_K * RVQ_D;
    const unsigned short* bmp = cb_mid + (size_t)l * RVQ_K * RVQ_D;
    const float* cnBl = cnormB + (size_t)l * RVQ_K;
    const float* cnl = cnorm + (size_t)l * RVQ_K;
    const float* cbl = cb + (size_t)l * RVQ_K * RVQ_D;

    int cand[4] = {0, 0, 0, 0};

#pragma unroll
    for (int pass = 0; pass < 2; ++pass) {
      // ---- A-fragment regen for this pass's two 16-point tiles ----
      short8 afr[2][2][2];
#pragma unroll
      for (int tl = 0; tl < 2; ++tl) {
        const int t = pass * 2 + tl;
        const int p = t * 16 + m;
        int j0 = 0, j1 = 0, j2 = 0;
        if (l > 0) j0 = __shfl(ci0, p);
        if (l > 1) j1 = __shfl(ci1, p);
        if (l > 2) j2 = __shfl(ci2, p);
        const float* fp = feat + (size_t)(base + p) * RVQ_D;
        const float* c0p = cb + (size_t)j0 * RVQ_D;
        const float* c1p = cb + ((size_t)RVQ_K + j1) * RVQ_D;
        const float* c2p = cb + ((size_t)2 * RVQ_K + j2) * RVQ_D;
#pragma unroll
        for (int oct = 0; oct < 2; ++oct) {
          const int dof = oct * 32 + q * 8;
          float v[8];
          load8(fp + dof, v);
          if (l > 0) {
            float c[8];
            load8(c0p + dof, c);
#pragma unroll
            for (int e = 0; e < 8; ++e) v[e] -= c[e];
          }
          if (l > 1) {
            float c[8];
            load8(c1p + dof, c);
#pragma unroll
            for (int e = 0; e < 8; ++e) v[e] -= c[e];
          }
          if (l > 2) {
            float c[8];
            load8(c2p + dof, c);
#pragma unroll
            for (int e = 0; e < 8; ++e) v[e] -= c[e];
          }
#pragma unroll
          for (int e = 0; e < 8; ++e) {
            unsigned short h0, h1;
            split2(v[e], h0, h1);
            afr[tl][0][oct][e] = (short)h0;
            afr[tl][1][oct][e] = (short)h1;
          }
        }
      }

      // ---- packed top-2 MFMA scan, double-buffered B ----
      unsigned p1[2][4], p2[2][4];
#pragma unroll
      for (int tl = 0; tl < 2; ++tl)
#pragma unroll
        for (int r2 = 0; r2 < 4; ++r2) {
          p1[tl][r2] = 0xFFFFFFFFu;
          p2[tl][r2] = 0xFFFFFFFFu;
        }

      short8 bA[2][2], bB[2][2];
      float ccA, ccB;
      load_bt(bh, bmp, cnBl, 0, m, q, bA, ccA);

      for (int nt = 0; nt < RVQ_K / 16; nt += 2) {
        load_bt(bh, bmp, cnBl, nt + 1, m, q, bB, ccB);
        {  // even tile
          floatx4 acc[2];
#pragma unroll
          for (int tl = 0; tl < 2; ++tl) {
            acc[tl][0] = ccA; acc[tl][1] = ccA;
            acc[tl][2] = ccA; acc[tl][3] = ccA;
          }
#pragma unroll
          for (int s = 0; s < 3; ++s)
#pragma unroll
            for (int oct = 0; oct < 2; ++oct)
#pragma unroll
              for (int tl = 0; tl < 2; ++tl)
                acc[tl] = __builtin_amdgcn_mfma_f32_16x16x32_bf16(
                    afr[tl][AC[s]][oct], bA[BC[s]][oct], acc[tl], 0, 0, 0);
          unsigned nbits = (unsigned)nt;
#pragma unroll
          for (int tl = 0; tl < 2; ++tl)
#pragma unroll
            for (int r2 = 0; r2 < 4; ++r2) {
              unsigned u =
                  (__float_as_uint(acc[tl][r2]) & 0xFFFFFFC0u) | nbits;
              p2[tl][r2] = med3u(p1[tl][r2], p2[tl][r2], u);
              p1[tl][r2] = p1[tl][r2] < u ? p1[tl][r2] : u;
            }
        }
        int ntn = (nt + 2 < RVQ_K / 16) ? nt + 2 : nt;
        load_bt(bh, bmp, cnBl, ntn, m, q, bA, ccA);
        {  // odd tile
          floatx4 acc[2];
#pragma unroll
          for (int tl = 0; tl < 2; ++tl) {
            acc[tl][0] = ccB; acc[tl][1] = ccB;
            acc[tl][2] = ccB; acc[tl][3] = ccB;
          }
#pragma unroll
          for (int s = 0; s < 3; ++s)
#pragma unroll
            for (int oct = 0; oct < 2; ++oct)
#pragma unroll
              for (int tl = 0; tl < 2; ++tl)
                acc[tl] = __builtin_amdgcn_mfma_f32_16x16x32_bf16(
                    afr[tl][AC[s]][oct], bB[BC[s]][oct], acc[tl], 0, 0, 0);
          unsigned nbits = (unsigned)(nt + 1);
#pragma unroll
          for (int tl = 0; tl < 2; ++tl)
#pragma unroll
            for (int r2 = 0; r2 < 4; ++r2) {
              unsigned u =
                  (__float_as_uint(acc[tl][r2]) & 0xFFFFFFC0u) | nbits;
              p2[tl][r2] = med3u(p1[tl][r2], p2[tl][r2], u);
              p1[tl][r2] = p1[tl][r2] < u ? p1[tl][r2] : u;
            }
        }
      }

      // ---- top-4 per point via 4 masked butterfly-min passes ----
      const int srcl = ((lane >> 2) & 3) << 4;
#pragma unroll
      for (int tl = 0; tl < 2; ++tl) {
        const int t = pass * 2 + tl;
#pragma unroll
        for (int r2 = 0; r2 < 4; ++r2) {
          unsigned a = p1[tl][r2], b = p2[tl][r2];
          int ka = (int)((a & 63u) << 4) | m;
          int kb = (int)((b & 63u) << 4) | m;
          unsigned va = (a & 0xFFFFFC00u) | (unsigned)ka;  // 10-bit k embedded
          unsigned vb = (b & 0xFFFFFC00u) | (unsigned)kb;
          if (vb < va) { unsigned tu = va; va = vb; vb = tu; }
          int ck[4];
#pragma unroll
          for (int pss = 0; pss < 4; ++pss) {
            unsigned gm = va;
#pragma unroll
            for (int off = 1; off <= 8; off <<= 1) {
              unsigned o = (unsigned)__shfl_xor((int)gm, off);
              gm = gm < o ? gm : o;
            }
            ck[pss] = (int)(gm & 1023u);
            bool hit = (va == gm);
            va = hit ? vb : va;
            vb = hit ? 0xFFFFFFFFu : vb;
          }
          int v1 = __shfl(ck[0], srcl);
          int v2 = __shfl(ck[1], srcl);
          int v3 = __shfl(ck[2], srcl);
          int v4 = __shfl(ck[3], srcl);
          bool take = (q == t) && ((lane & 3) == r2);
          if (take) { cand[0] = v1; cand[1] = v2; cand[2] = v3; cand[3] = v4; }
        }
      }
    }  // pass

    // ---- exact fp32 rescue, STREAMED (no r_[64] array) ----
    // Sort candidates ascending (tie -> lowest index wins, as before).
    {
      int tmp;
      if (cand[0] > cand[1]) { tmp = cand[0]; cand[0] = cand[1]; cand[1] = tmp; }
      if (cand[2] > cand[3]) { tmp = cand[2]; cand[2] = cand[3]; cand[3] = tmp; }
      if (cand[0] > cand[2]) { tmp = cand[0]; cand[0] = cand[2]; cand[2] = tmp; }
      if (cand[1] > cand[3]) { tmp = cand[1]; cand[1] = cand[3]; cand[3] = tmp; }
      if (cand[1] > cand[2]) { tmp = cand[1]; cand[1] = cand[2]; cand[2] = tmp; }
    }

    const float4* f4p = (const float4*)(feat + (size_t)g * RVQ_D);
    const float4* c0p4 = (const float4*)(cb + (size_t)ci0 * RVQ_D);
    const float4* c1p4 = (const float4*)(cb + ((size_t)RVQ_K + ci1) * RVQ_D);
    const float4* c2p4 = (const float4*)(cb + ((size_t)2 * RVQ_K + ci2) * RVQ_D);

    float sc0, sc1, sc2, sc3;
    // Pass 1: rr + dots for cand[0], cand[1]. Accumulator chains and op
    // order are identical to the original r_[]-based code -> bit-identical.
    {
      const float4* k0 = (const float4*)(cbl + (size_t)cand[0] * RVQ_D);
      const float4* k1 = (const float4*)(cbl + (size_t)cand[1] * RVQ_D);
      float s0 = 0.f, s1 = 0.f, s2 = 0.f, s3 = 0.f;
      float a00 = 0.f, a01 = 0.f, a02 = 0.f, a03 = 0.f;
      float a10 = 0.f, a11 = 0.f, a12 = 0.f, a13 = 0.f;
#pragma unroll
      for (int i = 0; i < 16; ++i) {
        float4 fv = f4p[i];
        float rx = fv.x, ry = fv.y, rz = fv.z, rw = fv.w;
        if (l > 0) {
          float4 v = c0p4[i];
          rx -= v.x; ry -= v.y; rz -= v.z; rw -= v.w;
        }
        if (l > 1) {
          float4 v = c1p4[i];
          rx -= v.x; ry -= v.y; rz -= v.z; rw -= v.w;
        }
        if (l > 2) {
          float4 v = c2p4[i];
          rx -= v.x; ry -= v.y; rz -= v.z; rw -= v.w;
        }
        s0 = fmaf(rx, rx, s0); s1 = fmaf(ry, ry, s1);
        s2 = fmaf(rz, rz, s2); s3 = fmaf(rw, rw, s3);
        float4 kv0 = k0[i];
        a00 = fmaf(rx, kv0.x, a00); a01 = fmaf(ry, kv0.y, a01);
        a02 = fmaf(rz, kv0.z, a02); a03 = fmaf(rw, kv0.w, a03);
        float4 kv1 = k1[i];
        a10 = fmaf(rx, kv1.x, a10); a11 = fmaf(ry, kv1.y, a11);
        a12 = fmaf(rz, kv1.z, a12); a13 = fmaf(rw, kv1.w, a13);
      }
      const float rr = (s0 + s1) + (s2 + s3);
      float dot0 = (a00 + a01) + (a02 + a03);
      float dot1 = (a10 + a11) + (a12 + a13);
      sc0 = (rr - 2.0f * dot0) + cnl[cand[0]];
      sc1 = (rr - 2.0f * dot1) + cnl[cand[1]];
    }
    // Pass 2: dots for cand[2], cand[3] (residual chunks recomputed with the
    // exact same ops -> identical values).
    {
      const float4* k2 = (const float4*)(cbl + (size_t)cand[2] * RVQ_D);
      const float4* k3 = (const float4*)(cbl + (size_t)cand[3] * RVQ_D);
      float s0 = 0.f, s1 = 0.f, s2 = 0.f, s3 = 0.f;
      float a20 = 0.f, a21 = 0.f, a22 = 0.f, a23 = 0.f;
      float a30 = 0.f, a31 = 0.f, a32 = 0.f, a33 = 0.f;
#pragma unroll
      for (int i = 0; i < 16; ++i) {
        float4 fv = f4p[i];
        float rx = fv.x, ry = fv.y, rz = fv.z, rw = fv.w;
        if (l > 0) {
          float4 v = c0p4[i];
          rx -= v.x; ry -= v.y; rz -= v.z; rw -= v.w;
        }
        if (l > 1) {
          float4 v = c1p4[i];
          rx -= v.x; ry -= v.y; rz -= v.z; rw -= v.w;
        }
        if (l > 2) {
          float4 v = c2p4[i];
          rx -= v.x; ry -= v.y; rz -= v.z; rw -= v.w;
        }
        s0 = fmaf(rx, rx, s0); s1 = fmaf(ry, ry, s1);
        s2 = fmaf(rz, rz, s2); s3 = fmaf(rw, rw, s3);
        float4 kv2 = k2[i];
        a20 = fmaf(rx, kv2.x, a20); a21 = fmaf(ry, kv2.y, a21);
        a22 = fmaf(rz, kv2.z, a22); a23 = fmaf(rw, kv2.w, a23);
        float4 kv3 = k3[i];
        a30 = fmaf(rx, kv3.x, a30); a31 = fmaf(ry, kv3.y, a31);
        a32 = fmaf(rz, kv3.z, a32); a33 = fmaf(rw, kv3.w, a33);
      }
      const float rr = (s0 + s1) + (s2 + s3);
      float dot2 = (a20 + a21) + (a22 + a23);
      float dot3 = (a30 + a31) + (a32 + a33);
      sc2 = (rr - 2.0f * dot2) + cnl[cand[2]];
      sc3 = (rr - 2.0f * dot3) + cnl[cand[3]];
    }

    float best = INFINITY;
    int ci = 0;
    if (sc0 < best) { best = sc0; ci = cand[0]; }
    if (sc1 < best) { best = sc1; ci = cand[1]; }
    if (sc2 < best) { best = sc2; ci = cand[2]; }
    if (sc3 < best) { best = sc3; ci = cand[3]; }

    if (l == 0) ci0 = ci;
    else if (l == 1) ci1 = ci;
    else if (l == 2) ci2 = ci;

    if (l == RVQ_L - 1) {
      // out = features - final residual (rn = r - c_ci), streamed, exact fp32
      const float4* crow = (const float4*)(cbl + (size_t)ci * RVQ_D);
      float4* o4 = (float4*)(out_q + (size_t)g * RVQ_D);
#pragma unroll
      for (int i = 0; i < 16; ++i) {
        float4 fv = f4p[i];
        float rx = fv.x, ry = fv.y, rz = fv.z, rw = fv.w;
        {
          float4 v = c0p4[i];
          rx -= v.x; ry -= v.y; rz -= v.z; rw -= v.w;
        }
        {
          float4 v = c1p4[i];
          rx -= v.x; ry -= v.y; rz -= v.z; rw -= v.w;
        }
        {
          float4 v = c2p4[i];
          rx -= v.x; ry -= v.y; rz -= v.z; rw -= v.w;
        }
        float4 cv = crow[i];
        float rn0 = rx - cv.x;
        float rn1 = ry - cv.y;
        float rn2 = rz - cv.z;
        float rn3 = rw - cv.w;
        float4 o;
        o.x = fv.x - rn0;
        o.y = fv.y - rn1;
        o.z = fv.z - rn2;
        o.w = fv.w - rn3;
        o4[i] = o;
      }
    }
    out_idx[(size_t)l * RVQ_N + g] = (float)ci;
  }
}

extern "C" void kernel_launch(void* const* d_in, const int* in_sizes, int n_in,
                              void* d_out, int out_size, void* d_ws,
                              size_t ws_size, hipStream_t stream) {
  const float* features = (const float*)d_in[0];   // [N, D]
  const float* codebooks = (const float*)d_in[1];  // [L, K, D]
  float* out_q = (float*)d_out;                    // [N, D]
  float* out_idx = (float*)d_out + (size_t)RVQ_N * RVQ_D;  // [L, N]

  const size_t comp_elems = (size_t)RVQ_L * RVQ_K * RVQ_D;  // 262144
  unsigned short* cb_hi = (unsigned short*)d_ws;
  unsigned short* cb_mid = cb_hi + comp_elems;
  float* cnorm = (float*)(cb_mid + comp_elems);   // [L*K] raw
  float* cnormB = cnorm + (size_t)RVQ_L * RVQ_K;  // [L*K] +256 biased

  hipLaunchKernelGGL(rvq_prep_split, dim3(comp_elems / 256), dim3(256), 0,
                     stream, codebooks, cb_hi, cb_mid);
  hipLaunchKernelGGL(rvq_cnorm_kernel, dim3((RVQ_L * RVQ_K) / 256), dim3(256),
                     0, stream, codebooks, cnorm, cnormB);
  hipLaunchKernelGGL(rvq_mfma_kernel, dim3(RVQ_N / 256), dim3(256), 0, stream,
                     features, codebooks, cb_hi, cb_mid, cnorm, cnormB, out_q,
                     out_idx);
}

// Round 4
// 969.772 us; speedup vs baseline: 2.2178x; 2.2178x over previous
//
#include <hip/hip_runtime.h>
#include <math.h>

constexpr int RVQ_N = 262144;
constexpr int RVQ_D = 64;
constexpr int RVQ_L = 4;
constexpr int RVQ_K = 1024;

typedef __attribute__((ext_vector_type(8))) short short8;
typedef __attribute__((ext_vector_type(4))) float floatx4;

// ---- bf16 split helpers (RNE) ----
__device__ __forceinline__ unsigned short f2bf(float f) {
  unsigned int u = __float_as_uint(f);
  u += 0x7fffu + ((u >> 16) & 1u);
  return (unsigned short)(u >> 16);
}
__device__ __forceinline__ float bf2f(unsigned short h) {
  return __uint_as_float(((unsigned int)h) << 16);
}
__device__ __forceinline__ void split2(float x, unsigned short& h0,
                                       unsigned short& h1) {
  h0 = f2bf(x);
  float r1 = x - bf2f(h0);
  h1 = f2bf(r1);
}
__device__ __forceinline__ void load8(const float* p, float* v) {
  float4 a = *(const float4*)p;
  float4 b = *(const float4*)(p + 4);
  v[0] = a.x; v[1] = a.y; v[2] = a.z; v[3] = a.w;
  v[4] = b.x; v[5] = b.y; v[6] = b.z; v[7] = b.w;
}

// top-2 insert helper: median of {p1,p2,u} is the new second-best (p1<=p2).
__device__ __forceinline__ unsigned med3u(unsigned a, unsigned b, unsigned c) {
  unsigned d;
  asm("v_med3_u32 %0, %1, %2, %3" : "=v"(d) : "v"(a), "v"(b), "v"(c));
  return d;
}

// ---------------------------------------------------------------------------
// Prep 1: split -2*codebook into hi/mid bf16 arrays [L*K*D each]
// ---------------------------------------------------------------------------
__global__ __launch_bounds__(256) void rvq_prep_split(
    const float* __restrict__ cb, unsigned short* __restrict__ bh,
    unsigned short* __restrict__ bm) {
  int i = blockIdx.x * 256 + threadIdx.x;
  float c2 = -2.0f * cb[i];
  unsigned short h0, h1;
  split2(c2, h0, h1);
  bh[i] = h0;
  bm[i] = h1;
}

// ---------------------------------------------------------------------------
// Prep 2: per-center squared norms. Raw (for rescue) + biased (+256 so MFMA
// scores = ||r-c||^2 + 256 > 0 -> uint-compare monotone).
// ---------------------------------------------------------------------------
__global__ __launch_bounds__(256) void rvq_cnorm_kernel(
    const float* __restrict__ cb, float* __restrict__ cnorm,
    float* __restrict__ cnormB) {
  int i = blockIdx.x * blockDim.x + threadIdx.x;
  const float* c = cb + (size_t)i * RVQ_D;
  float a0 = 0.f, a1 = 0.f, a2 = 0.f, a3 = 0.f;
#pragma unroll
  for (int d = 0; d < RVQ_D; d += 4) {
    float4 v = *reinterpret_cast<const float4*>(c + d);
    a0 = fmaf(v.x, v.x, a0);
    a1 = fmaf(v.y, v.y, a1);
    a2 = fmaf(v.z, v.z, a2);
    a3 = fmaf(v.w, v.w, a3);
  }
  float s = (a0 + a1) + (a2 + a3);
  cnorm[i] = s;
  cnormB[i] = s + 256.0f;
}

// B-tile fragment loader: hi/mid x 2 dim-octets + biased cnorm
__device__ __forceinline__ void load_bt(const unsigned short* __restrict__ bh,
                                        const unsigned short* __restrict__ bmp,
                                        const float* __restrict__ cnl, int nt,
                                        int m, int q, short8 (&b)[2][2],
                                        float& cc) {
  size_t rowoff = (size_t)(nt * 16 + m) * RVQ_D + q * 8;
  b[0][0] = *(const short8*)(bh + rowoff);
  b[0][1] = *(const short8*)(bh + rowoff + 32);
  b[1][0] = *(const short8*)(bmp + rowoff);
  b[1][1] = *(const short8*)(bmp + rowoff + 32);
  cc = cnl[nt * 16 + m];
}

// ---------------------------------------------------------------------------
// Main fused kernel. ONE WAVE PER BLOCK (64 threads, grid = N/64): waves are
// fully independent (no LDS / barriers), so shrinking block granularity is
// free and smooths the occupancy tail (4096 blocks over ~3072 resident slots
// drains in fine steps instead of a 1/3-occupancy second round at block=256).
// Register budget is the proven R0 one: __launch_bounds__(64,3) == 170 regs,
// no spill (R1/R2 showed the 128-reg 4-wave budget is not reachable).
// s_setprio(1) wraps each MFMA cluster: resident waves are at uncorrelated
// phases (scan/selection/rescue), the regime where setprio measurably helps.
// Packed-uint top-2 scan nominates; exact fp32 rescue decides.
// ---------------------------------------------------------------------------
__global__ __launch_bounds__(64, 3) void rvq_mfma_kernel(
    const float* __restrict__ feat, const float* __restrict__ cb,
    const unsigned short* __restrict__ cb_hi,
    const unsigned short* __restrict__ cb_mid,
    const float* __restrict__ cnorm, const float* __restrict__ cnormB,
    float* __restrict__ out_q, float* __restrict__ out_idx) {
  const int lane = threadIdx.x & 63;
  const int m = lane & 15;  // column (B center / C col / A row)
  const int q = lane >> 4;  // quad (k-octet / C row-group)
  const int base = blockIdx.x * 64;  // wave's first point
  const int g = base + lane;         // this lane's own point

  int ci0 = 0, ci1 = 0, ci2 = 0;  // chosen-index chain (own point)

  // products kept: hi*hi, hi*mid, mid*hi
  constexpr int AC[3] = {0, 0, 1};
  constexpr int BC[3] = {0, 1, 0};

#pragma unroll
  for (int l = 0; l < RVQ_L; ++l) {
    const unsigned short* bh = cb_hi + (size_t)l * RVQ_K * RVQ_D;
    const unsigned short* bmp = cb_mid + (size_t)l * RVQ_K * RVQ_D;
    const float* cnBl = cnormB + (size_t)l * RVQ_K;
    const float* cnl = cnorm + (size_t)l * RVQ_K;
    const float* cbl = cb + (size_t)l * RVQ_K * RVQ_D;

    // ---- A-fragment regen from (features, chain), in fragment layout ----
    short8 afr[4][2][2];
#pragma unroll
    for (int t = 0; t < 4; ++t) {
      const int p = t * 16 + m;
      int j0 = 0, j1 = 0, j2 = 0;
      if (l > 0) j0 = __shfl(ci0, p);
      if (l > 1) j1 = __shfl(ci1, p);
      if (l > 2) j2 = __shfl(ci2, p);
      const float* fp = feat + (size_t)(base + p) * RVQ_D;
      const float* c0p = cb + (size_t)j0 * RVQ_D;
      const float* c1p = cb + ((size_t)RVQ_K + j1) * RVQ_D;
      const float* c2p = cb + ((size_t)2 * RVQ_K + j2) * RVQ_D;
#pragma unroll
      for (int oct = 0; oct < 2; ++oct) {
        const int dof = oct * 32 + q * 8;
        float v[8];
        load8(fp + dof, v);
        if (l > 0) {
          float c[8];
          load8(c0p + dof, c);
#pragma unroll
          for (int e = 0; e < 8; ++e) v[e] -= c[e];
        }
        if (l > 1) {
          float c[8];
          load8(c1p + dof, c);
#pragma unroll
          for (int e = 0; e < 8; ++e) v[e] -= c[e];
        }
        if (l > 2) {
          float c[8];
          load8(c2p + dof, c);
#pragma unroll
          for (int e = 0; e < 8; ++e) v[e] -= c[e];
        }
#pragma unroll
        for (int e = 0; e < 8; ++e) {
          unsigned short h0, h1;
          split2(v[e], h0, h1);
          afr[t][0][oct][e] = (short)h0;
          afr[t][1][oct][e] = (short)h1;
        }
      }
    }

    // ---- packed top-2 MFMA scan, double-buffered B ----
    unsigned p1[4][4], p2[4][4];
#pragma unroll
    for (int t = 0; t < 4; ++t)
#pragma unroll
      for (int r2 = 0; r2 < 4; ++r2) {
        p1[t][r2] = 0xFFFFFFFFu;
        p2[t][r2] = 0xFFFFFFFFu;
      }

    short8 bA[2][2], bB[2][2];
    float ccA, ccB;
    load_bt(bh, bmp, cnBl, 0, m, q, bA, ccA);

    for (int nt = 0; nt < RVQ_K / 16; nt += 2) {
      load_bt(bh, bmp, cnBl, nt + 1, m, q, bB, ccB);
      {  // even tile
        floatx4 acc[4];
#pragma unroll
        for (int t = 0; t < 4; ++t) {
          acc[t][0] = ccA; acc[t][1] = ccA; acc[t][2] = ccA; acc[t][3] = ccA;
        }
        __builtin_amdgcn_s_setprio(1);
#pragma unroll
        for (int s = 0; s < 3; ++s)
#pragma unroll
          for (int oct = 0; oct < 2; ++oct)
#pragma unroll
            for (int t = 0; t < 4; ++t)
              acc[t] = __builtin_amdgcn_mfma_f32_16x16x32_bf16(
                  afr[t][AC[s]][oct], bA[BC[s]][oct], acc[t], 0, 0, 0);
        __builtin_amdgcn_s_setprio(0);
        unsigned nbits = (unsigned)nt;
#pragma unroll
        for (int t = 0; t < 4; ++t)
#pragma unroll
          for (int r2 = 0; r2 < 4; ++r2) {
            unsigned u = (__float_as_uint(acc[t][r2]) & 0xFFFFFFC0u) | nbits;
            p2[t][r2] = med3u(p1[t][r2], p2[t][r2], u);
            p1[t][r2] = p1[t][r2] < u ? p1[t][r2] : u;
          }
      }
      int ntn = (nt + 2 < RVQ_K / 16) ? nt + 2 : nt;
      load_bt(bh, bmp, cnBl, ntn, m, q, bA, ccA);
      {  // odd tile
        floatx4 acc[4];
#pragma unroll
        for (int t = 0; t < 4; ++t) {
          acc[t][0] = ccB; acc[t][1] = ccB; acc[t][2] = ccB; acc[t][3] = ccB;
        }
        __builtin_amdgcn_s_setprio(1);
#pragma unroll
        for (int s = 0; s < 3; ++s)
#pragma unroll
          for (int oct = 0; oct < 2; ++oct)
#pragma unroll
            for (int t = 0; t < 4; ++t)
              acc[t] = __builtin_amdgcn_mfma_f32_16x16x32_bf16(
                  afr[t][AC[s]][oct], bB[BC[s]][oct], acc[t], 0, 0, 0);
        __builtin_amdgcn_s_setprio(0);
        unsigned nbits = (unsigned)(nt + 1);
#pragma unroll
        for (int t = 0; t < 4; ++t)
#pragma unroll
          for (int r2 = 0; r2 < 4; ++r2) {
            unsigned u = (__float_as_uint(acc[t][r2]) & 0xFFFFFFC0u) | nbits;
            p2[t][r2] = med3u(p1[t][r2], p2[t][r2], u);
            p1[t][r2] = p1[t][r2] < u ? p1[t][r2] : u;
          }
      }
    }

    // ---- top-4 per point via 4 masked butterfly-min passes ----
    int cand[4] = {0, 0, 0, 0};
    const int srcl = ((lane >> 2) & 3) << 4;
#pragma unroll
    for (int t = 0; t < 4; ++t)
#pragma unroll
      for (int r2 = 0; r2 < 4; ++r2) {
        unsigned a = p1[t][r2], b = p2[t][r2];
        int ka = (int)((a & 63u) << 4) | m;
        int kb = (int)((b & 63u) << 4) | m;
        unsigned va = (a & 0xFFFFFC00u) | (unsigned)ka;  // 10-bit k embedded
        unsigned vb = (b & 0xFFFFFC00u) | (unsigned)kb;
        if (vb < va) { unsigned tu = va; va = vb; vb = tu; }
        int ck[4];
#pragma unroll
        for (int pass = 0; pass < 4; ++pass) {
          unsigned gm = va;
#pragma unroll
          for (int off = 1; off <= 8; off <<= 1) {
            unsigned o = (unsigned)__shfl_xor((int)gm, off);
            gm = gm < o ? gm : o;
          }
          ck[pass] = (int)(gm & 1023u);
          bool hit = (va == gm);
          va = hit ? vb : va;
          vb = hit ? 0xFFFFFFFFu : vb;
        }
        int v1 = __shfl(ck[0], srcl);
        int v2 = __shfl(ck[1], srcl);
        int v3 = __shfl(ck[2], srcl);
        int v4 = __shfl(ck[3], srcl);
        bool take = (q == t) && ((lane & 3) == r2);
        if (take) { cand[0] = v1; cand[1] = v2; cand[2] = v3; cand[3] = v4; }
      }

    // ---- exact fp32 rescue on own point ----
    {
      int tmp;
      if (cand[0] > cand[1]) { tmp = cand[0]; cand[0] = cand[1]; cand[1] = tmp; }
      if (cand[2] > cand[3]) { tmp = cand[2]; cand[2] = cand[3]; cand[3] = tmp; }
      if (cand[0] > cand[2]) { tmp = cand[0]; cand[0] = cand[2]; cand[2] = tmp; }
      if (cand[1] > cand[3]) { tmp = cand[1]; cand[1] = cand[3]; cand[3] = tmp; }
      if (cand[1] > cand[2]) { tmp = cand[1]; cand[1] = cand[2]; cand[2] = tmp; }
    }

    float r_[RVQ_D];
    {
      const float4* f4p = (const float4*)(feat + (size_t)g * RVQ_D);
#pragma unroll
      for (int i = 0; i < 16; ++i) {
        float4 v = f4p[i];
        r_[4 * i + 0] = v.x; r_[4 * i + 1] = v.y;
        r_[4 * i + 2] = v.z; r_[4 * i + 3] = v.w;
      }
      if (l > 0) {
        const float4* cp = (const float4*)(cb + (size_t)ci0 * RVQ_D);
#pragma unroll
        for (int i = 0; i < 16; ++i) {
          float4 v = cp[i];
          r_[4 * i + 0] -= v.x; r_[4 * i + 1] -= v.y;
          r_[4 * i + 2] -= v.z; r_[4 * i + 3] -= v.w;
        }
      }
      if (l > 1) {
        const float4* cp = (const float4*)(cb + ((size_t)RVQ_K + ci1) * RVQ_D);
#pragma unroll
        for (int i = 0; i < 16; ++i) {
          float4 v = cp[i];
          r_[4 * i + 0] -= v.x; r_[4 * i + 1] -= v.y;
          r_[4 * i + 2] -= v.z; r_[4 * i + 3] -= v.w;
        }
      }
      if (l > 2) {
        const float4* cp =
            (const float4*)(cb + ((size_t)2 * RVQ_K + ci2) * RVQ_D);
#pragma unroll
        for (int i = 0; i < 16; ++i) {
          float4 v = cp[i];
          r_[4 * i + 0] -= v.x; r_[4 * i + 1] -= v.y;
          r_[4 * i + 2] -= v.z; r_[4 * i + 3] -= v.w;
        }
      }
    }

    float s0 = 0.f, s1 = 0.f, s2 = 0.f, s3 = 0.f;
#pragma unroll
    for (int i = 0; i < 16; ++i) {
      s0 = fmaf(r_[4 * i + 0], r_[4 * i + 0], s0);
      s1 = fmaf(r_[4 * i + 1], r_[4 * i + 1], s1);
      s2 = fmaf(r_[4 * i + 2], r_[4 * i + 2], s2);
      s3 = fmaf(r_[4 * i + 3], r_[4 * i + 3], s3);
    }
    const float rr = (s0 + s1) + (s2 + s3);

    float best = INFINITY;
    int ci = 0;
#pragma unroll
    for (int jc = 0; jc < 4; ++jc) {
      int k = cand[jc];
      const float4* c4 = (const float4*)(cbl + (size_t)k * RVQ_D);
      float a0 = 0.f, a1 = 0.f, a2 = 0.f, a3 = 0.f;
#pragma unroll
      for (int i = 0; i < 16; ++i) {
        float4 v = c4[i];
        a0 = fmaf(r_[4 * i + 0], v.x, a0);
        a1 = fmaf(r_[4 * i + 1], v.y, a1);
        a2 = fmaf(r_[4 * i + 2], v.z, a2);
        a3 = fmaf(r_[4 * i + 3], v.w, a3);
      }
      float dot = (a0 + a1) + (a2 + a3);
      float score = (rr - 2.0f * dot) + cnl[k];
      if (score < best) {
        best = score;
        ci = k;
      }
    }

    if (l == 0) ci0 = ci;
    else if (l == 1) ci1 = ci;
    else if (l == 2) ci2 = ci;

    if (l == RVQ_L - 1) {
      // out = features - final residual (rn = r - c_ci), exact fp32
      const float4* crow = (const float4*)(cbl + (size_t)ci * RVQ_D);
      const float4* f4p = (const float4*)(feat + (size_t)g * RVQ_D);
      float4* o4 = (float4*)(out_q + (size_t)g * RVQ_D);
#pragma unroll
      for (int i = 0; i < 16; ++i) {
        float4 cv = crow[i];
        float4 fv = f4p[i];
        float rn0 = r_[4 * i + 0] - cv.x;
        float rn1 = r_[4 * i + 1] - cv.y;
        float rn2 = r_[4 * i + 2] - cv.z;
        float rn3 = r_[4 * i + 3] - cv.w;
        float4 o;
        o.x = fv.x - rn0;
        o.y = fv.y - rn1;
        o.z = fv.z - rn2;
        o.w = fv.w - rn3;
        o4[i] = o;
      }
    }
    out_idx[(size_t)l * RVQ_N + g] = (float)ci;
  }
}

extern "C" void kernel_launch(void* const* d_in, const int* in_sizes, int n_in,
                              void* d_out, int out_size, void* d_ws,
                              size_t ws_size, hipStream_t stream) {
  const float* features = (const float*)d_in[0];   // [N, D]
  const float* codebooks = (const float*)d_in[1];  // [L, K, D]
  float* out_q = (float*)d_out;                    // [N, D]
  float* out_idx = (float*)d_out + (size_t)RVQ_N * RVQ_D;  // [L, N]

  const size_t comp_elems = (size_t)RVQ_L * RVQ_K * RVQ_D;  // 262144
  unsigned short* cb_hi = (unsigned short*)d_ws;
  unsigned short* cb_mid = cb_hi + comp_elems;
  float* cnorm = (float*)(cb_mid + comp_elems);   // [L*K] raw
  float* cnormB = cnorm + (size_t)RVQ_L * RVQ_K;  // [L*K] +256 biased

  hipLaunchKernelGGL(rvq_prep_split, dim3(comp_elems / 256), dim3(256), 0,
                     stream, codebooks, cb_hi, cb_mid);
  hipLaunchKernelGGL(rvq_cnorm_kernel, dim3((RVQ_L * RVQ_K) / 256), dim3(256),
                     0, stream, codebooks, cnorm, cnormB);
  hipLaunchKernelGGL(rvq_mfma_kernel, dim3(RVQ_N / 64), dim3(64), 0, stream,
                     features, codebooks, cb_hi, cb_mid, cnorm, cnormB, out_q,
                     out_idx);
}

// Round 5
// 934.014 us; speedup vs baseline: 2.3027x; 1.0383x over previous
//
#include <hip/hip_runtime.h>
#include <math.h>

constexpr int RVQ_N = 262144;
constexpr int RVQ_D = 64;
constexpr int RVQ_L = 4;
constexpr int RVQ_K = 1024;

typedef __attribute__((ext_vector_type(8))) short short8;
typedef __attribute__((ext_vector_type(4))) float floatx4;

// ---- bf16 split helpers (RNE) ----
__device__ __forceinline__ unsigned short f2bf(float f) {
  unsigned int u = __float_as_uint(f);
  u += 0x7fffu + ((u >> 16) & 1u);
  return (unsigned short)(u >> 16);
}
__device__ __forceinline__ float bf2f(unsigned short h) {
  return __uint_as_float(((unsigned int)h) << 16);
}
__device__ __forceinline__ void split2(float x, unsigned short& h0,
                                       unsigned short& h1) {
  h0 = f2bf(x);
  float r1 = x - bf2f(h0);
  h1 = f2bf(r1);
}
__device__ __forceinline__ void load8(const float* p, float* v) {
  float4 a = *(const float4*)p;
  float4 b = *(const float4*)(p + 4);
  v[0] = a.x; v[1] = a.y; v[2] = a.z; v[3] = a.w;
  v[4] = b.x; v[5] = b.y; v[6] = b.z; v[7] = b.w;
}

// top-2 insert helper: median of {p1,p2,u} is the new second-best (p1<=p2).
__device__ __forceinline__ unsigned med3u(unsigned a, unsigned b, unsigned c) {
  unsigned d;
  asm("v_med3_u32 %0, %1, %2, %3" : "=v"(d) : "v"(a), "v"(b), "v"(c));
  return d;
}

// ---------------------------------------------------------------------------
// Prep 1: split -2*codebook into hi/mid bf16 arrays [L*K*D each]
// ---------------------------------------------------------------------------
__global__ __launch_bounds__(256) void rvq_prep_split(
    const float* __restrict__ cb, unsigned short* __restrict__ bh,
    unsigned short* __restrict__ bm) {
  int i = blockIdx.x * 256 + threadIdx.x;
  float c2 = -2.0f * cb[i];
  unsigned short h0, h1;
  split2(c2, h0, h1);
  bh[i] = h0;
  bm[i] = h1;
}

// ---------------------------------------------------------------------------
// Prep 2: per-center squared norms. Raw (for rescue) + biased (+256 so MFMA
// scores = ||r-c||^2 + 256 > 0 -> uint-compare monotone).
// ---------------------------------------------------------------------------
__global__ __launch_bounds__(256) void rvq_cnorm_kernel(
    const float* __restrict__ cb, float* __restrict__ cnorm,
    float* __restrict__ cnormB) {
  int i = blockIdx.x * blockDim.x + threadIdx.x;
  const float* c = cb + (size_t)i * RVQ_D;
  float a0 = 0.f, a1 = 0.f, a2 = 0.f, a3 = 0.f;
#pragma unroll
  for (int d = 0; d < RVQ_D; d += 4) {
    float4 v = *reinterpret_cast<const float4*>(c + d);
    a0 = fmaf(v.x, v.x, a0);
    a1 = fmaf(v.y, v.y, a1);
    a2 = fmaf(v.z, v.z, a2);
    a3 = fmaf(v.w, v.w, a3);
  }
  float s = (a0 + a1) + (a2 + a3);
  cnorm[i] = s;
  cnormB[i] = s + 256.0f;
}

// B-tile fragment loader: hi/mid x 2 dim-octets + biased cnorm
__device__ __forceinline__ void load_bt(const unsigned short* __restrict__ bh,
                                        const unsigned short* __restrict__ bmp,
                                        const float* __restrict__ cnl, int nt,
                                        int m, int q, short8 (&b)[2][2],
                                        float& cc) {
  size_t rowoff = (size_t)(nt * 16 + m) * RVQ_D + q * 8;
  b[0][0] = *(const short8*)(bh + rowoff);
  b[0][1] = *(const short8*)(bh + rowoff + 32);
  b[1][0] = *(const short8*)(bmp + rowoff);
  b[1][1] = *(const short8*)(bmp + rowoff + 32);
  cc = cnl[nt * 16 + m];
}

// ---------------------------------------------------------------------------
// Main fused kernel. ONE WAVE PER BLOCK (64 threads, grid = N/64).
// KEY CHANGE (R5): the level loop is ROLLED (#pragma unroll 1). Fully
// unrolled, the body was ~10k instructions (~70-80 KB of code) -- more than
// 2x the 32 KB L1I, and resident waves sit at uncorrelated phases, so
// I-fetch thrashes; this is the hypothesized source of the ~57% no-issue
// cycles (all pipes <25% busy, HBM 11%, occupancy nominal). Rolled, the body
// executes 4x from the same PCs (~20 KB, L1I-resident). The l>0/l>1/l>2
// guards become wave-uniform branches; all register arrays keep static
// indexing inside the body. Arithmetic is R4-verbatim -> identical results.
// Packed-uint top-2 scan nominates; exact fp32 rescue decides.
// ---------------------------------------------------------------------------
__global__ __launch_bounds__(64, 3) void rvq_mfma_kernel(
    const float* __restrict__ feat, const float* __restrict__ cb,
    const unsigned short* __restrict__ cb_hi,
    const unsigned short* __restrict__ cb_mid,
    const float* __restrict__ cnorm, const float* __restrict__ cnormB,
    float* __restrict__ out_q, float* __restrict__ out_idx) {
  const int lane = threadIdx.x & 63;
  const int m = lane & 15;  // column (B center / C col / A row)
  const int q = lane >> 4;  // quad (k-octet / C row-group)
  const int base = blockIdx.x * 64;  // wave's first point
  const int g = base + lane;         // this lane's own point

  int ci0 = 0, ci1 = 0, ci2 = 0;  // chosen-index chain (own point)

  // products kept: hi*hi, hi*mid, mid*hi
  constexpr int AC[3] = {0, 0, 1};
  constexpr int BC[3] = {0, 1, 0};

#pragma unroll 1
  for (int l = 0; l < RVQ_L; ++l) {
    const unsigned short* bh = cb_hi + (size_t)l * RVQ_K * RVQ_D;
    const unsigned short* bmp = cb_mid + (size_t)l * RVQ_K * RVQ_D;
    const float* cnBl = cnormB + (size_t)l * RVQ_K;
    const float* cnl = cnorm + (size_t)l * RVQ_K;
    const float* cbl = cb + (size_t)l * RVQ_K * RVQ_D;

    // ---- A-fragment regen from (features, chain), in fragment layout ----
    short8 afr[4][2][2];
#pragma unroll
    for (int t = 0; t < 4; ++t) {
      const int p = t * 16 + m;
      int j0 = 0, j1 = 0, j2 = 0;
      if (l > 0) j0 = __shfl(ci0, p);
      if (l > 1) j1 = __shfl(ci1, p);
      if (l > 2) j2 = __shfl(ci2, p);
      const float* fp = feat + (size_t)(base + p) * RVQ_D;
      const float* c0p = cb + (size_t)j0 * RVQ_D;
      const float* c1p = cb + ((size_t)RVQ_K + j1) * RVQ_D;
      const float* c2p = cb + ((size_t)2 * RVQ_K + j2) * RVQ_D;
#pragma unroll
      for (int oct = 0; oct < 2; ++oct) {
        const int dof = oct * 32 + q * 8;
        float v[8];
        load8(fp + dof, v);
        if (l > 0) {
          float c[8];
          load8(c0p + dof, c);
#pragma unroll
          for (int e = 0; e < 8; ++e) v[e] -= c[e];
        }
        if (l > 1) {
          float c[8];
          load8(c1p + dof, c);
#pragma unroll
          for (int e = 0; e < 8; ++e) v[e] -= c[e];
        }
        if (l > 2) {
          float c[8];
          load8(c2p + dof, c);
#pragma unroll
          for (int e = 0; e < 8; ++e) v[e] -= c[e];
        }
#pragma unroll
        for (int e = 0; e < 8; ++e) {
          unsigned short h0, h1;
          split2(v[e], h0, h1);
          afr[t][0][oct][e] = (short)h0;
          afr[t][1][oct][e] = (short)h1;
        }
      }
    }

    // ---- packed top-2 MFMA scan, double-buffered B ----
    unsigned p1[4][4], p2[4][4];
#pragma unroll
    for (int t = 0; t < 4; ++t)
#pragma unroll
      for (int r2 = 0; r2 < 4; ++r2) {
        p1[t][r2] = 0xFFFFFFFFu;
        p2[t][r2] = 0xFFFFFFFFu;
      }

    short8 bA[2][2], bB[2][2];
    float ccA, ccB;
    load_bt(bh, bmp, cnBl, 0, m, q, bA, ccA);

    for (int nt = 0; nt < RVQ_K / 16; nt += 2) {
      load_bt(bh, bmp, cnBl, nt + 1, m, q, bB, ccB);
      {  // even tile
        floatx4 acc[4];
#pragma unroll
        for (int t = 0; t < 4; ++t) {
          acc[t][0] = ccA; acc[t][1] = ccA; acc[t][2] = ccA; acc[t][3] = ccA;
        }
        __builtin_amdgcn_s_setprio(1);
#pragma unroll
        for (int s = 0; s < 3; ++s)
#pragma unroll
          for (int oct = 0; oct < 2; ++oct)
#pragma unroll
            for (int t = 0; t < 4; ++t)
              acc[t] = __builtin_amdgcn_mfma_f32_16x16x32_bf16(
                  afr[t][AC[s]][oct], bA[BC[s]][oct], acc[t], 0, 0, 0);
        __builtin_amdgcn_s_setprio(0);
        unsigned nbits = (unsigned)nt;
#pragma unroll
        for (int t = 0; t < 4; ++t)
#pragma unroll
          for (int r2 = 0; r2 < 4; ++r2) {
            unsigned u = (__float_as_uint(acc[t][r2]) & 0xFFFFFFC0u) | nbits;
            p2[t][r2] = med3u(p1[t][r2], p2[t][r2], u);
            p1[t][r2] = p1[t][r2] < u ? p1[t][r2] : u;
          }
      }
      int ntn = (nt + 2 < RVQ_K / 16) ? nt + 2 : nt;
      load_bt(bh, bmp, cnBl, ntn, m, q, bA, ccA);
      {  // odd tile
        floatx4 acc[4];
#pragma unroll
        for (int t = 0; t < 4; ++t) {
          acc[t][0] = ccB; acc[t][1] = ccB; acc[t][2] = ccB; acc[t][3] = ccB;
        }
        __builtin_amdgcn_s_setprio(1);
#pragma unroll
        for (int s = 0; s < 3; ++s)
#pragma unroll
          for (int oct = 0; oct < 2; ++oct)
#pragma unroll
            for (int t = 0; t < 4; ++t)
              acc[t] = __builtin_amdgcn_mfma_f32_16x16x32_bf16(
                  afr[t][AC[s]][oct], bB[BC[s]][oct], acc[t], 0, 0, 0);
        __builtin_amdgcn_s_setprio(0);
        unsigned nbits = (unsigned)(nt + 1);
#pragma unroll
        for (int t = 0; t < 4; ++t)
#pragma unroll
          for (int r2 = 0; r2 < 4; ++r2) {
            unsigned u = (__float_as_uint(acc[t][r2]) & 0xFFFFFFC0u) | nbits;
            p2[t][r2] = med3u(p1[t][r2], p2[t][r2], u);
            p1[t][r2] = p1[t][r2] < u ? p1[t][r2] : u;
          }
      }
    }

    // ---- top-4 per point via 4 masked butterfly-min passes ----
    int cand[4] = {0, 0, 0, 0};
    const int srcl = ((lane >> 2) & 3) << 4;
#pragma unroll
    for (int t = 0; t < 4; ++t)
#pragma unroll
      for (int r2 = 0; r2 < 4; ++r2) {
        unsigned a = p1[t][r2], b = p2[t][r2];
        int ka = (int)((a & 63u) << 4) | m;
        int kb = (int)((b & 63u) << 4) | m;
        unsigned va = (a & 0xFFFFFC00u) | (unsigned)ka;  // 10-bit k embedded
        unsigned vb = (b & 0xFFFFFC00u) | (unsigned)kb;
        if (vb < va) { unsigned tu = va; va = vb; vb = tu; }
        int ck[4];
#pragma unroll
        for (int pass = 0; pass < 4; ++pass) {
          unsigned gm = va;
#pragma unroll
          for (int off = 1; off <= 8; off <<= 1) {
            unsigned o = (unsigned)__shfl_xor((int)gm, off);
            gm = gm < o ? gm : o;
          }
          ck[pass] = (int)(gm & 1023u);
          bool hit = (va == gm);
          va = hit ? vb : va;
          vb = hit ? 0xFFFFFFFFu : vb;
        }
        int v1 = __shfl(ck[0], srcl);
        int v2 = __shfl(ck[1], srcl);
        int v3 = __shfl(ck[2], srcl);
        int v4 = __shfl(ck[3], srcl);
        bool take = (q == t) && ((lane & 3) == r2);
        if (take) { cand[0] = v1; cand[1] = v2; cand[2] = v3; cand[3] = v4; }
      }

    // ---- exact fp32 rescue on own point ----
    {
      int tmp;
      if (cand[0] > cand[1]) { tmp = cand[0]; cand[0] = cand[1]; cand[1] = tmp; }
      if (cand[2] > cand[3]) { tmp = cand[2]; cand[2] = cand[3]; cand[3] = tmp; }
      if (cand[0] > cand[2]) { tmp = cand[0]; cand[0] = cand[2]; cand[2] = tmp; }
      if (cand[1] > cand[3]) { tmp = cand[1]; cand[1] = cand[3]; cand[3] = tmp; }
      if (cand[1] > cand[2]) { tmp = cand[1]; cand[1] = cand[2]; cand[2] = tmp; }
    }

    float r_[RVQ_D];
    {
      const float4* f4p = (const float4*)(feat + (size_t)g * RVQ_D);
#pragma unroll
      for (int i = 0; i < 16; ++i) {
        float4 v = f4p[i];
        r_[4 * i + 0] = v.x; r_[4 * i + 1] = v.y;
        r_[4 * i + 2] = v.z; r_[4 * i + 3] = v.w;
      }
      if (l > 0) {
        const float4* cp = (const float4*)(cb + (size_t)ci0 * RVQ_D);
#pragma unroll
        for (int i = 0; i < 16; ++i) {
          float4 v = cp[i];
          r_[4 * i + 0] -= v.x; r_[4 * i + 1] -= v.y;
          r_[4 * i + 2] -= v.z; r_[4 * i + 3] -= v.w;
        }
      }
      if (l > 1) {
        const float4* cp = (const float4*)(cb + ((size_t)RVQ_K + ci1) * RVQ_D);
#pragma unroll
        for (int i = 0; i < 16; ++i) {
          float4 v = cp[i];
          r_[4 * i + 0] -= v.x; r_[4 * i + 1] -= v.y;
          r_[4 * i + 2] -= v.z; r_[4 * i + 3] -= v.w;
        }
      }
      if (l > 2) {
        const float4* cp =
            (const float4*)(cb + ((size_t)2 * RVQ_K + ci2) * RVQ_D);
#pragma unroll
        for (int i = 0; i < 16; ++i) {
          float4 v = cp[i];
          r_[4 * i + 0] -= v.x; r_[4 * i + 1] -= v.y;
          r_[4 * i + 2] -= v.z; r_[4 * i + 3] -= v.w;
        }
      }
    }

    float s0 = 0.f, s1 = 0.f, s2 = 0.f, s3 = 0.f;
#pragma unroll
    for (int i = 0; i < 16; ++i) {
      s0 = fmaf(r_[4 * i + 0], r_[4 * i + 0], s0);
      s1 = fmaf(r_[4 * i + 1], r_[4 * i + 1], s1);
      s2 = fmaf(r_[4 * i + 2], r_[4 * i + 2], s2);
      s3 = fmaf(r_[4 * i + 3], r_[4 * i + 3], s3);
    }
    const float rr = (s0 + s1) + (s2 + s3);

    float best = INFINITY;
    int ci = 0;
#pragma unroll
    for (int jc = 0; jc < 4; ++jc) {
      int k = cand[jc];
      const float4* c4 = (const float4*)(cbl + (size_t)k * RVQ_D);
      float a0 = 0.f, a1 = 0.f, a2 = 0.f, a3 = 0.f;
#pragma unroll
      for (int i = 0; i < 16; ++i) {
        float4 v = c4[i];
        a0 = fmaf(r_[4 * i + 0], v.x, a0);
        a1 = fmaf(r_[4 * i + 1], v.y, a1);
        a2 = fmaf(r_[4 * i + 2], v.z, a2);
        a3 = fmaf(r_[4 * i + 3], v.w, a3);
      }
      float dot = (a0 + a1) + (a2 + a3);
      float score = (rr - 2.0f * dot) + cnl[k];
      if (score < best) {
        best = score;
        ci = k;
      }
    }

    if (l == 0) ci0 = ci;
    else if (l == 1) ci1 = ci;
    else if (l == 2) ci2 = ci;

    if (l == RVQ_L - 1) {
      // out = features - final residual (rn = r - c_ci), exact fp32
      const float4* crow = (const float4*)(cbl + (size_t)ci * RVQ_D);
      const float4* f4p = (const float4*)(feat + (size_t)g * RVQ_D);
      float4* o4 = (float4*)(out_q + (size_t)g * RVQ_D);
#pragma unroll
      for (int i = 0; i < 16; ++i) {
        float4 cv = crow[i];
        float4 fv = f4p[i];
        float rn0 = r_[4 * i + 0] - cv.x;
        float rn1 = r_[4 * i + 1] - cv.y;
        float rn2 = r_[4 * i + 2] - cv.z;
        float rn3 = r_[4 * i + 3] - cv.w;
        float4 o;
        o.x = fv.x - rn0;
        o.y = fv.y - rn1;
        o.z = fv.z - rn2;
        o.w = fv.w - rn3;
        o4[i] = o;
      }
    }
    out_idx[(size_t)l * RVQ_N + g] = (float)ci;
  }
}

extern "C" void kernel_launch(void* const* d_in, const int* in_sizes, int n_in,
                              void* d_out, int out_size, void* d_ws,
                              size_t ws_size, hipStream_t stream) {
  const float* features = (const float*)d_in[0];   // [N, D]
  const float* codebooks = (const float*)d_in[1];  // [L, K, D]
  float* out_q = (float*)d_out;                    // [N, D]
  float* out_idx = (float*)d_out + (size_t)RVQ_N * RVQ_D;  // [L, N]

  const size_t comp_elems = (size_t)RVQ_L * RVQ_K * RVQ_D;  // 262144
  unsigned short* cb_hi = (unsigned short*)d_ws;
  unsigned short* cb_mid = cb_hi + comp_elems;
  float* cnorm = (float*)(cb_mid + comp_elems);   // [L*K] raw
  float* cnormB = cnorm + (size_t)RVQ_L * RVQ_K;  // [L*K] +256 biased

  hipLaunchKernelGGL(rvq_prep_split, dim3(comp_elems / 256), dim3(256), 0,
                     stream, codebooks, cb_hi, cb_mid);
  hipLaunchKernelGGL(rvq_cnorm_kernel, dim3((RVQ_L * RVQ_K) / 256), dim3(256),
                     0, stream, codebooks, cnorm, cnormB);
  hipLaunchKernelGGL(rvq_mfma_kernel, dim3(RVQ_N / 64), dim3(64), 0, stream,
                     features, codebooks, cb_hi, cb_mid, cnorm, cnormB, out_q,
                     out_idx);
}

// Round 6
// 918.160 us; speedup vs baseline: 2.3424x; 1.0173x over previous
//
#include <hip/hip_runtime.h>
#include <math.h>

constexpr int RVQ_N = 262144;
constexpr int RVQ_D = 64;
constexpr int RVQ_L = 4;
constexpr int RVQ_K = 1024;

typedef __attribute__((ext_vector_type(8))) short short8;
typedef __attribute__((ext_vector_type(4))) float floatx4;

// ---- bf16 split helpers (RNE) ----
__device__ __forceinline__ unsigned short f2bf(float f) {
  unsigned int u = __float_as_uint(f);
  u += 0x7fffu + ((u >> 16) & 1u);
  return (unsigned short)(u >> 16);
}
__device__ __forceinline__ float bf2f(unsigned short h) {
  return __uint_as_float(((unsigned int)h) << 16);
}
__device__ __forceinline__ void split2(float x, unsigned short& h0,
                                       unsigned short& h1) {
  h0 = f2bf(x);
  float r1 = x - bf2f(h0);
  h1 = f2bf(r1);
}
__device__ __forceinline__ void load8(const float* p, float* v) {
  float4 a = *(const float4*)p;
  float4 b = *(const float4*)(p + 4);
  v[0] = a.x; v[1] = a.y; v[2] = a.z; v[3] = a.w;
  v[4] = b.x; v[5] = b.y; v[6] = b.z; v[7] = b.w;
}

// top-2 insert helper: median of {p1,p2,u} is the new second-best (p1<=p2).
__device__ __forceinline__ unsigned med3u(unsigned a, unsigned b, unsigned c) {
  unsigned d;
  asm("v_med3_u32 %0, %1, %2, %3" : "=v"(d) : "v"(a), "v"(b), "v"(c));
  return d;
}

// min over the 16-lane DPP row via rotate-reduce: 4 dependent VALU steps
// (row_ror:1/2/4/8 + v_min_u32) instead of 4 dependent DS shuffles (~35cy
// each). All lanes of the row end with the row-global min — same value the
// old __shfl_xor(1,2,4,8) butterfly produced (offsets <16 never crossed the
// 16-lane row). Full exec mask at all call sites (no divergence).
__device__ __forceinline__ unsigned rowmin16(unsigned x) {
  unsigned y;
  y = (unsigned)__builtin_amdgcn_update_dpp(0, (int)x, 0x121, 0xF, 0xF, true);
  x = x < y ? x : y;  // row_ror:1
  y = (unsigned)__builtin_amdgcn_update_dpp(0, (int)x, 0x122, 0xF, 0xF, true);
  x = x < y ? x : y;  // row_ror:2
  y = (unsigned)__builtin_amdgcn_update_dpp(0, (int)x, 0x124, 0xF, 0xF, true);
  x = x < y ? x : y;  // row_ror:4
  y = (unsigned)__builtin_amdgcn_update_dpp(0, (int)x, 0x128, 0xF, 0xF, true);
  x = x < y ? x : y;  // row_ror:8
  return x;
}

// ---------------------------------------------------------------------------
// Prep 1: split -2*codebook into hi/mid bf16 arrays [L*K*D each]
// ---------------------------------------------------------------------------
__global__ __launch_bounds__(256) void rvq_prep_split(
    const float* __restrict__ cb, unsigned short* __restrict__ bh,
    unsigned short* __restrict__ bm) {
  int i = blockIdx.x * 256 + threadIdx.x;
  float c2 = -2.0f * cb[i];
  unsigned short h0, h1;
  split2(c2, h0, h1);
  bh[i] = h0;
  bm[i] = h1;
}

// ---------------------------------------------------------------------------
// Prep 2: per-center squared norms. Raw (for rescue) + biased (+256 so MFMA
// scores = ||r-c||^2 + 256 > 0 -> uint-compare monotone).
// ---------------------------------------------------------------------------
__global__ __launch_bounds__(256) void rvq_cnorm_kernel(
    const float* __restrict__ cb, float* __restrict__ cnorm,
    float* __restrict__ cnormB) {
  int i = blockIdx.x * blockDim.x + threadIdx.x;
  const float* c = cb + (size_t)i * RVQ_D;
  float a0 = 0.f, a1 = 0.f, a2 = 0.f, a3 = 0.f;
#pragma unroll
  for (int d = 0; d < RVQ_D; d += 4) {
    float4 v = *reinterpret_cast<const float4*>(c + d);
    a0 = fmaf(v.x, v.x, a0);
    a1 = fmaf(v.y, v.y, a1);
    a2 = fmaf(v.z, v.z, a2);
    a3 = fmaf(v.w, v.w, a3);
  }
  float s = (a0 + a1) + (a2 + a3);
  cnorm[i] = s;
  cnormB[i] = s + 256.0f;
}

// B-tile fragment loader: hi/mid x 2 dim-octets + biased cnorm
__device__ __forceinline__ void load_bt(const unsigned short* __restrict__ bh,
                                        const unsigned short* __restrict__ bmp,
                                        const float* __restrict__ cnl, int nt,
                                        int m, int q, short8 (&b)[2][2],
                                        float& cc) {
  size_t rowoff = (size_t)(nt * 16 + m) * RVQ_D + q * 8;
  b[0][0] = *(const short8*)(bh + rowoff);
  b[0][1] = *(const short8*)(bh + rowoff + 32);
  b[1][0] = *(const short8*)(bmp + rowoff);
  b[1][1] = *(const short8*)(bmp + rowoff + 32);
  cc = cnl[nt * 16 + m];
}

// ---------------------------------------------------------------------------
// Main fused kernel. ONE WAVE PER BLOCK (64 threads, grid = N/64); level
// loop rolled (R5: code fits L1I). R6 changes:
//  (a) selection's intra-row reduce uses DPP rotate-reduce (rowmin16)
//      instead of 4 dependent DS shuffles -- cuts ~256 serial DS ops/level
//      of nearly pure latency out of the one architecturally-serial phase;
//  (b) each tile's first MFMA takes the cnorm splat directly as C-input
//      (D != C), removing 16 acc-init movs per tile. Per-acc accumulation
//      order unchanged -> bit-identical scores.
// Packed-uint top-2 scan nominates; exact fp32 rescue decides.
// ---------------------------------------------------------------------------
__global__ __launch_bounds__(64, 3) void rvq_mfma_kernel(
    const float* __restrict__ feat, const float* __restrict__ cb,
    const unsigned short* __restrict__ cb_hi,
    const unsigned short* __restrict__ cb_mid,
    const float* __restrict__ cnorm, const float* __restrict__ cnormB,
    float* __restrict__ out_q, float* __restrict__ out_idx) {
  const int lane = threadIdx.x & 63;
  const int m = lane & 15;  // column (B center / C col / A row)
  const int q = lane >> 4;  // quad (k-octet / C row-group)
  const int base = blockIdx.x * 64;  // wave's first point
  const int g = base + lane;         // this lane's own point

  int ci0 = 0, ci1 = 0, ci2 = 0;  // chosen-index chain (own point)

  // products kept: hi*hi, hi*mid, mid*hi
  constexpr int AC[3] = {0, 0, 1};
  constexpr int BC[3] = {0, 1, 0};

#pragma unroll 1
  for (int l = 0; l < RVQ_L; ++l) {
    const unsigned short* bh = cb_hi + (size_t)l * RVQ_K * RVQ_D;
    const unsigned short* bmp = cb_mid + (size_t)l * RVQ_K * RVQ_D;
    const float* cnBl = cnormB + (size_t)l * RVQ_K;
    const float* cnl = cnorm + (size_t)l * RVQ_K;
    const float* cbl = cb + (size_t)l * RVQ_K * RVQ_D;

    // ---- A-fragment regen from (features, chain), in fragment layout ----
    short8 afr[4][2][2];
#pragma unroll
    for (int t = 0; t < 4; ++t) {
      const int p = t * 16 + m;
      int j0 = 0, j1 = 0, j2 = 0;
      if (l > 0) j0 = __shfl(ci0, p);
      if (l > 1) j1 = __shfl(ci1, p);
      if (l > 2) j2 = __shfl(ci2, p);
      const float* fp = feat + (size_t)(base + p) * RVQ_D;
      const float* c0p = cb + (size_t)j0 * RVQ_D;
      const float* c1p = cb + ((size_t)RVQ_K + j1) * RVQ_D;
      const float* c2p = cb + ((size_t)2 * RVQ_K + j2) * RVQ_D;
#pragma unroll
      for (int oct = 0; oct < 2; ++oct) {
        const int dof = oct * 32 + q * 8;
        float v[8];
        load8(fp + dof, v);
        if (l > 0) {
          float c[8];
          load8(c0p + dof, c);
#pragma unroll
          for (int e = 0; e < 8; ++e) v[e] -= c[e];
        }
        if (l > 1) {
          float c[8];
          load8(c1p + dof, c);
#pragma unroll
          for (int e = 0; e < 8; ++e) v[e] -= c[e];
        }
        if (l > 2) {
          float c[8];
          load8(c2p + dof, c);
#pragma unroll
          for (int e = 0; e < 8; ++e) v[e] -= c[e];
        }
#pragma unroll
        for (int e = 0; e < 8; ++e) {
          unsigned short h0, h1;
          split2(v[e], h0, h1);
          afr[t][0][oct][e] = (short)h0;
          afr[t][1][oct][e] = (short)h1;
        }
      }
    }

    // ---- packed top-2 MFMA scan, double-buffered B ----
    unsigned p1[4][4], p2[4][4];
#pragma unroll
    for (int t = 0; t < 4; ++t)
#pragma unroll
      for (int r2 = 0; r2 < 4; ++r2) {
        p1[t][r2] = 0xFFFFFFFFu;
        p2[t][r2] = 0xFFFFFFFFu;
      }

    short8 bA[2][2], bB[2][2];
    float ccA, ccB;
    load_bt(bh, bmp, cnBl, 0, m, q, bA, ccA);

    for (int nt = 0; nt < RVQ_K / 16; nt += 2) {
      load_bt(bh, bmp, cnBl, nt + 1, m, q, bB, ccB);
      {  // even tile
        floatx4 ccv;
        ccv[0] = ccA; ccv[1] = ccA; ccv[2] = ccA; ccv[3] = ccA;
        floatx4 acc[4];
        __builtin_amdgcn_s_setprio(1);
#pragma unroll
        for (int t = 0; t < 4; ++t) {
          floatx4 a = __builtin_amdgcn_mfma_f32_16x16x32_bf16(
              afr[t][AC[0]][0], bA[BC[0]][0], ccv, 0, 0, 0);
#pragma unroll
          for (int s = 0; s < 3; ++s)
#pragma unroll
            for (int oct = 0; oct < 2; ++oct) {
              if (s == 0 && oct == 0) continue;
              a = __builtin_amdgcn_mfma_f32_16x16x32_bf16(
                  afr[t][AC[s]][oct], bA[BC[s]][oct], a, 0, 0, 0);
            }
          acc[t] = a;
        }
        __builtin_amdgcn_s_setprio(0);
        unsigned nbits = (unsigned)nt;
#pragma unroll
        for (int t = 0; t < 4; ++t)
#pragma unroll
          for (int r2 = 0; r2 < 4; ++r2) {
            unsigned u = (__float_as_uint(acc[t][r2]) & 0xFFFFFFC0u) | nbits;
            p2[t][r2] = med3u(p1[t][r2], p2[t][r2], u);
            p1[t][r2] = p1[t][r2] < u ? p1[t][r2] : u;
          }
      }
      int ntn = (nt + 2 < RVQ_K / 16) ? nt + 2 : nt;
      load_bt(bh, bmp, cnBl, ntn, m, q, bA, ccA);
      {  // odd tile
        floatx4 ccv;
        ccv[0] = ccB; ccv[1] = ccB; ccv[2] = ccB; ccv[3] = ccB;
        floatx4 acc[4];
        __builtin_amdgcn_s_setprio(1);
#pragma unroll
        for (int t = 0; t < 4; ++t) {
          floatx4 a = __builtin_amdgcn_mfma_f32_16x16x32_bf16(
              afr[t][AC[0]][0], bB[BC[0]][0], ccv, 0, 0, 0);
#pragma unroll
          for (int s = 0; s < 3; ++s)
#pragma unroll
            for (int oct = 0; oct < 2; ++oct) {
              if (s == 0 && oct == 0) continue;
              a = __builtin_amdgcn_mfma_f32_16x16x32_bf16(
                  afr[t][AC[s]][oct], bB[BC[s]][oct], a, 0, 0, 0);
            }
          acc[t] = a;
        }
        __builtin_amdgcn_s_setprio(0);
        unsigned nbits = (unsigned)(nt + 1);
#pragma unroll
        for (int t = 0; t < 4; ++t)
#pragma unroll
          for (int r2 = 0; r2 < 4; ++r2) {
            unsigned u = (__float_as_uint(acc[t][r2]) & 0xFFFFFFC0u) | nbits;
            p2[t][r2] = med3u(p1[t][r2], p2[t][r2], u);
            p1[t][r2] = p1[t][r2] < u ? p1[t][r2] : u;
          }
      }
    }

    // ---- top-4 per point via 4 masked row-min passes (DPP reduce) ----
    int cand[4] = {0, 0, 0, 0};
    const int srcl = ((lane >> 2) & 3) << 4;
#pragma unroll
    for (int t = 0; t < 4; ++t)
#pragma unroll
      for (int r2 = 0; r2 < 4; ++r2) {
        unsigned a = p1[t][r2], b = p2[t][r2];
        int ka = (int)((a & 63u) << 4) | m;
        int kb = (int)((b & 63u) << 4) | m;
        unsigned va = (a & 0xFFFFFC00u) | (unsigned)ka;  // 10-bit k embedded
        unsigned vb = (b & 0xFFFFFC00u) | (unsigned)kb;
        if (vb < va) { unsigned tu = va; va = vb; vb = tu; }
        int ck[4];
#pragma unroll
        for (int pass = 0; pass < 4; ++pass) {
          unsigned gm = rowmin16(va);
          ck[pass] = (int)(gm & 1023u);
          bool hit = (va == gm);
          va = hit ? vb : va;
          vb = hit ? 0xFFFFFFFFu : vb;
        }
        int v1 = __shfl(ck[0], srcl);
        int v2 = __shfl(ck[1], srcl);
        int v3 = __shfl(ck[2], srcl);
        int v4 = __shfl(ck[3], srcl);
        bool take = (q == t) && ((lane & 3) == r2);
        if (take) { cand[0] = v1; cand[1] = v2; cand[2] = v3; cand[3] = v4; }
      }

    // ---- exact fp32 rescue on own point ----
    {
      int tmp;
      if (cand[0] > cand[1]) { tmp = cand[0]; cand[0] = cand[1]; cand[1] = tmp; }
      if (cand[2] > cand[3]) { tmp = cand[2]; cand[2] = cand[3]; cand[3] = tmp; }
      if (cand[0] > cand[2]) { tmp = cand[0]; cand[0] = cand[2]; cand[2] = tmp; }
      if (cand[1] > cand[3]) { tmp = cand[1]; cand[1] = cand[3]; cand[3] = tmp; }
      if (cand[1] > cand[2]) { tmp = cand[1]; cand[1] = cand[2]; cand[2] = tmp; }
    }

    float r_[RVQ_D];
    {
      const float4* f4p = (const float4*)(feat + (size_t)g * RVQ_D);
#pragma unroll
      for (int i = 0; i < 16; ++i) {
        float4 v = f4p[i];
        r_[4 * i + 0] = v.x; r_[4 * i + 1] = v.y;
        r_[4 * i + 2] = v.z; r_[4 * i + 3] = v.w;
      }
      if (l > 0) {
        const float4* cp = (const float4*)(cb + (size_t)ci0 * RVQ_D);
#pragma unroll
        for (int i = 0; i < 16; ++i) {
          float4 v = cp[i];
          r_[4 * i + 0] -= v.x; r_[4 * i + 1] -= v.y;
          r_[4 * i + 2] -= v.z; r_[4 * i + 3] -= v.w;
        }
      }
      if (l > 1) {
        const float4* cp = (const float4*)(cb + ((size_t)RVQ_K + ci1) * RVQ_D);
#pragma unroll
        for (int i = 0; i < 16; ++i) {
          float4 v = cp[i];
          r_[4 * i + 0] -= v.x; r_[4 * i + 1] -= v.y;
          r_[4 * i + 2] -= v.z; r_[4 * i + 3] -= v.w;
        }
      }
      if (l > 2) {
        const float4* cp =
            (const float4*)(cb + ((size_t)2 * RVQ_K + ci2) * RVQ_D);
#pragma unroll
        for (int i = 0; i < 16; ++i) {
          float4 v = cp[i];
          r_[4 * i + 0] -= v.x; r_[4 * i + 1] -= v.y;
          r_[4 * i + 2] -= v.z; r_[4 * i + 3] -= v.w;
        }
      }
    }

    float s0 = 0.f, s1 = 0.f, s2 = 0.f, s3 = 0.f;
#pragma unroll
    for (int i = 0; i < 16; ++i) {
      s0 = fmaf(r_[4 * i + 0], r_[4 * i + 0], s0);
      s1 = fmaf(r_[4 * i + 1], r_[4 * i + 1], s1);
      s2 = fmaf(r_[4 * i + 2], r_[4 * i + 2], s2);
      s3 = fmaf(r_[4 * i + 3], r_[4 * i + 3], s3);
    }
    const float rr = (s0 + s1) + (s2 + s3);

    float best = INFINITY;
    int ci = 0;
#pragma unroll
    for (int jc = 0; jc < 4; ++jc) {
      int k = cand[jc];
      const float4* c4 = (const float4*)(cbl + (size_t)k * RVQ_D);
      float a0 = 0.f, a1 = 0.f, a2 = 0.f, a3 = 0.f;
#pragma unroll
      for (int i = 0; i < 16; ++i) {
        float4 v = c4[i];
        a0 = fmaf(r_[4 * i + 0], v.x, a0);
        a1 = fmaf(r_[4 * i + 1], v.y, a1);
        a2 = fmaf(r_[4 * i + 2], v.z, a2);
        a3 = fmaf(r_[4 * i + 3], v.w, a3);
      }
      float dot = (a0 + a1) + (a2 + a3);
      float score = (rr - 2.0f * dot) + cnl[k];
      if (score < best) {
        best = score;
        ci = k;
      }
    }

    if (l == 0) ci0 = ci;
    else if (l == 1) ci1 = ci;
    else if (l == 2) ci2 = ci;

    if (l == RVQ_L - 1) {
      // out = features - final residual (rn = r - c_ci), exact fp32
      const float4* crow = (const float4*)(cbl + (size_t)ci * RVQ_D);
      const float4* f4p = (const float4*)(feat + (size_t)g * RVQ_D);
      float4* o4 = (float4*)(out_q + (size_t)g * RVQ_D);
#pragma unroll
      for (int i = 0; i < 16; ++i) {
        float4 cv = crow[i];
        float4 fv = f4p[i];
        float rn0 = r_[4 * i + 0] - cv.x;
        float rn1 = r_[4 * i + 1] - cv.y;
        float rn2 = r_[4 * i + 2] - cv.z;
        float rn3 = r_[4 * i + 3] - cv.w;
        float4 o;
        o.x = fv.x - rn0;
        o.y = fv.y - rn1;
        o.z = fv.z - rn2;
        o.w = fv.w - rn3;
        o4[i] = o;
      }
    }
    out_idx[(size_t)l * RVQ_N + g] = (float)ci;
  }
}

extern "C" void kernel_launch(void* const* d_in, const int* in_sizes, int n_in,
                              void* d_out, int out_size, void* d_ws,
                              size_t ws_size, hipStream_t stream) {
  const float* features = (const float*)d_in[0];   // [N, D]
  const float* codebooks = (const float*)d_in[1];  // [L, K, D]
  float* out_q = (float*)d_out;                    // [N, D]
  float* out_idx = (float*)d_out + (size_t)RVQ_N * RVQ_D;  // [L, N]

  const size_t comp_elems = (size_t)RVQ_L * RVQ_K * RVQ_D;  // 262144
  unsigned short* cb_hi = (unsigned short*)d_ws;
  unsigned short* cb_mid = cb_hi + comp_elems;
  float* cnorm = (float*)(cb_mid + comp_elems);   // [L*K] raw
  float* cnormB = cnorm + (size_t)RVQ_L * RVQ_K;  // [L*K] +256 biased

  hipLaunchKernelGGL(rvq_prep_split, dim3(comp_elems / 256), dim3(256), 0,
                     stream, codebooks, cb_hi, cb_mid);
  hipLaunchKernelGGL(rvq_cnorm_kernel, dim3((RVQ_L * RVQ_K) / 256), dim3(256),
                     0, stream, codebooks, cnorm, cnormB);
  hipLaunchKernelGGL(rvq_mfma_kernel, dim3(RVQ_N / 64), dim3(64), 0, stream,
                     features, codebooks, cb_hi, cb_mid, cnorm, cnormB, out_q,
                     out_idx);
}